// Round 1
// baseline (3746.737 us; speedup 1.0000x reference)
//
#include <hip/hip_runtime.h>
#include <math.h>

#define HH 512
#define BB 64
#define SS 48
#define EE 512
#define G4 2048
#define EPSF 1e-5f

// ---- block-wide sum + sumsq over 256 threads (4 waves of 64) ----
__device__ inline float2 blockReduceSumSq(float s, float q, float* red) {
  #pragma unroll
  for (int off = 32; off > 0; off >>= 1) {
    s += __shfl_down(s, off);
    q += __shfl_down(q, off);
  }
  int lane = threadIdx.x & 63;
  int wid  = threadIdx.x >> 6;
  if (lane == 0) { red[wid] = s; red[4 + wid] = q; }
  __syncthreads();
  float ts = red[0] + red[1] + red[2] + red[3];
  float tq = red[4] + red[5] + red[6] + red[7];
  __syncthreads();
  return make_float2(ts, tq);
}

// ---- generic C[m,n] = sum_k A[m*K+k] * W[n*K+k]; 64x64 tile, BK=16 ----
__global__ __launch_bounds__(256)
void gemm_nt64(const float* __restrict__ A, const float* __restrict__ Wm,
               float* __restrict__ C, int N, int K) {
  __shared__ float As[16][65];
  __shared__ float Bs[16][65];
  const int bm = blockIdx.y * 64;
  const int bn = blockIdx.x * 64;
  const int tid = threadIdx.x;
  const int lrow = tid >> 2;
  const int lkk  = (tid & 3) << 2;
  const int tx = tid & 15;
  const int ty = tid >> 4;
  float acc[4][4] = {};
  for (int k0 = 0; k0 < K; k0 += 16) {
    float4 av = *(const float4*)(A  + (size_t)(bm + lrow) * K + k0 + lkk);
    float4 bv = *(const float4*)(Wm + (size_t)(bn + lrow) * K + k0 + lkk);
    As[lkk+0][lrow] = av.x; As[lkk+1][lrow] = av.y; As[lkk+2][lrow] = av.z; As[lkk+3][lrow] = av.w;
    Bs[lkk+0][lrow] = bv.x; Bs[lkk+1][lrow] = bv.y; Bs[lkk+2][lrow] = bv.z; Bs[lkk+3][lrow] = bv.w;
    __syncthreads();
    #pragma unroll
    for (int k = 0; k < 16; ++k) {
      float a[4], b[4];
      #pragma unroll
      for (int i = 0; i < 4; ++i) a[i] = As[k][ty*4+i];
      #pragma unroll
      for (int j = 0; j < 4; ++j) b[j] = Bs[k][tx*4+j];
      #pragma unroll
      for (int i = 0; i < 4; ++i)
        #pragma unroll
        for (int j = 0; j < 4; ++j) acc[i][j] += a[i]*b[j];
    }
    __syncthreads();
  }
  for (int i = 0; i < 4; ++i)
    for (int j = 0; j < 4; ++j)
      C[(size_t)(bm + ty*4 + i) * N + bn + tx*4 + j] = acc[i][j];
}

// ---- recurrent step GEMM: R[d][b][n] = sum_k h[d][b][k] * Whh[d][n][k] ----
// tile: 64 b x 32 n, BK=16, grid (G4/32, 1, 2)
__global__ __launch_bounds__(256)
void gemm_step(const float* __restrict__ h, const float* __restrict__ Whh,
               float* __restrict__ R) {
  __shared__ float As[16][65];
  __shared__ float Bs[16][33];
  const int d = blockIdx.z;
  const int bn = blockIdx.x * 32;
  const int tid = threadIdx.x;
  const float* Ab = h   + (size_t)d * BB * HH;
  const float* Wb = Whh + (size_t)d * G4 * HH;
  const int lrow = tid >> 2, lkk = (tid & 3) << 2;
  const int tx = tid & 7;
  const int ty = tid >> 3;
  float acc[2][4] = {};
  for (int k0 = 0; k0 < HH; k0 += 16) {
    float4 av = *(const float4*)(Ab + (size_t)lrow * HH + k0 + lkk);
    As[lkk+0][lrow]=av.x; As[lkk+1][lrow]=av.y; As[lkk+2][lrow]=av.z; As[lkk+3][lrow]=av.w;
    if (tid < 128) {
      float4 bv = *(const float4*)(Wb + (size_t)(bn + lrow) * HH + k0 + lkk);
      Bs[lkk+0][lrow]=bv.x; Bs[lkk+1][lrow]=bv.y; Bs[lkk+2][lrow]=bv.z; Bs[lkk+3][lrow]=bv.w;
    }
    __syncthreads();
    #pragma unroll
    for (int k = 0; k < 16; ++k) {
      float b[4];
      #pragma unroll
      for (int j = 0; j < 4; ++j) b[j] = Bs[k][tx*4+j];
      float a0 = As[k][ty*2], a1 = As[k][ty*2+1];
      #pragma unroll
      for (int j = 0; j < 4; ++j) { acc[0][j] += a0*b[j]; acc[1][j] += a1*b[j]; }
    }
    __syncthreads();
  }
  float* Rb = R + (size_t)d * BB * G4;
  for (int i = 0; i < 2; ++i)
    for (int j = 0; j < 4; ++j)
      Rb[(size_t)(ty*2+i) * G4 + bn + tx*4 + j] = acc[i][j];
}

// ---- in-place LayerNorm on rows of 2048; d = row / rows_per_d ----
__global__ __launch_bounds__(256)
void ln_rows(float* __restrict__ X, const float* __restrict__ gamma,
             const float* __restrict__ beta, int rows_per_d) {
  __shared__ float red[8];
  const int row = blockIdx.x;
  const int d = row / rows_per_d;
  float* xr = X + (size_t)row * G4;
  const float* gg = gamma + (size_t)d * G4;
  const float* bb = beta  + (size_t)d * G4;
  float s = 0.f, q = 0.f;
  float v[8];
  #pragma unroll
  for (int it = 0; it < 8; ++it) {
    float x = xr[threadIdx.x + it*256];
    v[it] = x; s += x; q += x*x;
  }
  float2 t = blockReduceSumSq(s, q, red);
  float mu = t.x * (1.f/G4);
  float var = t.y * (1.f/G4) - mu*mu;
  float rstd = rsqrtf(var + EPSF);
  #pragma unroll
  for (int it = 0; it < 8; ++it) {
    int jc = threadIdx.x + it*256;
    xr[jc] = (v[it]-mu)*rstd*gg[jc] + bb[jc];
  }
}

// ---- fused per-(d,b) row: LN(R) -> gates -> c update -> LN(c) -> h ----
__global__ __launch_bounds__(256)
void lstm_update(const float* __restrict__ R,
                 const float* __restrict__ g_in, long g_db_stride, long g_off0, long g_off1,
                 const float* __restrict__ ln_hh_g, const float* __restrict__ ln_hh_b,
                 const float* __restrict__ ln_ho_g, const float* __restrict__ ln_ho_b,
                 float* __restrict__ h, float* __restrict__ c) {
  __shared__ float red[8];
  const int b = blockIdx.x, d = blockIdx.y;
  const int db = d * BB + b;
  const float* Rr = R + (size_t)db * G4;
  const float* gr = g_in + (size_t)db * g_db_stride + (d == 0 ? g_off0 : g_off1);
  const float* hg = ln_hh_g + (size_t)d * G4;
  const float* hb = ln_hh_b + (size_t)d * G4;
  const float* og = ln_ho_g + (size_t)d * HH;
  const float* ob = ln_ho_b + (size_t)d * HH;

  float s = 0.f, q = 0.f;
  float rv[8];
  #pragma unroll
  for (int it = 0; it < 8; ++it) {
    float x = Rr[threadIdx.x + it*256];
    rv[it] = x; s += x; q += x*x;
  }
  float2 t = blockReduceSumSq(s, q, red);
  float mu = t.x*(1.f/G4), var = t.y*(1.f/G4)-mu*mu, rstd = rsqrtf(var+EPSF);

  float cs = 0.f, cq = 0.f, cn[2], on[2];
  #pragma unroll
  for (int it = 0; it < 2; ++it) {
    int n = threadIdx.x + it*256;
    float gi  = gr[n]        + (rv[it]   - mu)*rstd*hg[n]        + hb[n];
    float gf  = gr[HH+n]     + (rv[2+it] - mu)*rstd*hg[HH+n]     + hb[HH+n];
    float go  = gr[2*HH+n]   + (rv[4+it] - mu)*rstd*hg[2*HH+n]   + hb[2*HH+n];
    float gt  = gr[3*HH+n]   + (rv[6+it] - mu)*rstd*hg[3*HH+n]   + hb[3*HH+n];
    float iv = 1.f/(1.f+expf(-gi));
    float fv = 1.f/(1.f+expf(-gf));
    float ov = 1.f/(1.f+expf(-go));
    float gv = tanhf(gt);
    float cold = c[(size_t)db*HH + n];
    float cnew = fv*cold + iv*gv;
    c[(size_t)db*HH + n] = cnew;
    cn[it] = cnew; on[it] = ov;
    cs += cnew; cq += cnew*cnew;
  }
  t = blockReduceSumSq(cs, cq, red);
  float muc = t.x*(1.f/HH), varc = t.y*(1.f/HH)-muc*muc, rstdc = rsqrtf(varc+EPSF);
  #pragma unroll
  for (int it = 0; it < 2; ++it) {
    int n = threadIdx.x + it*256;
    h[(size_t)db*HH + n] = on[it]*tanhf((cn[it]-muc)*rstdc*og[n] + ob[n]);
  }
}

// ---- out[b][d*H+n] = h[(d*B+b)*H+n]  (concat over directions) ----
__global__ void copy_concat(const float* __restrict__ h, float* __restrict__ dst) {
  int idx = blockIdx.x*256 + threadIdx.x;   // 2*BB*HH total
  int b = idx >> 10;
  int col = idx & 1023;
  int d = col >> 9, n = col & 511;
  dst[idx] = h[((size_t)(d*BB + b))*HH + n];
}

extern "C" void kernel_launch(void* const* d_in, const int* in_sizes, int n_in,
                              void* d_out, int out_size, void* d_ws, size_t ws_size,
                              hipStream_t stream) {
  const float* x        = (const float*)d_in[0];
  const float* w_ih0    = (const float*)d_in[2];
  const float* w_hh0    = (const float*)d_in[3];
  const float* ln_ih0_g = (const float*)d_in[4];
  const float* ln_ih0_b = (const float*)d_in[5];
  const float* ln_hh0_g = (const float*)d_in[6];
  const float* ln_hh0_b = (const float*)d_in[7];
  const float* ln_ho0_g = (const float*)d_in[8];
  const float* ln_ho0_b = (const float*)d_in[9];
  const float* w_ih1    = (const float*)d_in[10];
  const float* w_hh1    = (const float*)d_in[11];
  const float* ln_ih1_g = (const float*)d_in[12];
  const float* ln_ih1_b = (const float*)d_in[13];
  const float* ln_hh1_g = (const float*)d_in[14];
  const float* ln_hh1_b = (const float*)d_in[15];
  const float* ln_ho1_g = (const float*)d_in[16];
  const float* ln_ho1_b = (const float*)d_in[17];
  float* out = (float*)d_out;

  float* ws    = (float*)d_ws;
  float* G0    = ws;                          // [2][B][S][4H] = 12,582,912 f
  float* g1pre = G0 + (size_t)2*BB*SS*G4;     // [2][B][4H]    = 262,144 f
  float* R     = g1pre + (size_t)2*BB*G4;     // [2][B][4H]    = 262,144 f
  float* hbuf  = R + (size_t)2*BB*G4;         // [2][B][H]     = 65,536 f
  float* cbuf  = hbuf + (size_t)2*BB*HH;      // [2][B][H]
  float* xc    = cbuf + (size_t)2*BB*HH;      // [B][2H]

  // Phase A: G0[d] = x @ w_ih0[d]^T   rows r=(b*S+s) contiguous in x.
  dim3 gA(G4/64, (BB*SS)/64);
  for (int d = 0; d < 2; ++d)
    hipLaunchKernelGGL(gemm_nt64, gA, dim3(256), 0, stream,
        x, w_ih0 + (size_t)d*G4*EE, G0 + (size_t)d*BB*SS*G4, G4, EE);
  hipLaunchKernelGGL(ln_rows, dim3(2*BB*SS), dim3(256), 0, stream,
      G0, ln_ih0_g, ln_ih0_b, BB*SS);

  hipMemsetAsync(hbuf, 0, (size_t)2*BB*HH*sizeof(float), stream);
  hipMemsetAsync(cbuf, 0, (size_t)2*BB*HH*sizeof(float), stream);

  // Layer 0 scan: d=0 forward (s=t), d=1 backward (s=S-1-t)
  for (int t = 0; t < SS; ++t) {
    hipLaunchKernelGGL(gemm_step, dim3(G4/32, 1, 2), dim3(256), 0, stream, hbuf, w_hh0, R);
    hipLaunchKernelGGL(lstm_update, dim3(BB, 2), dim3(256), 0, stream,
        R, G0, (long)SS*G4, (long)t*G4, (long)(SS-1-t)*G4,
        ln_hh0_g, ln_hh0_b, ln_ho0_g, ln_ho0_b, hbuf, cbuf);
  }

  hipLaunchKernelGGL(copy_concat, dim3(2*BB*HH/256), dim3(256), 0, stream, hbuf, xc);

  // Layer 1 input projection (constant over time): g1pre[d] = xc @ w_ih1[d]^T
  for (int d = 0; d < 2; ++d)
    hipLaunchKernelGGL(gemm_nt64, dim3(G4/64, 1), dim3(256), 0, stream,
        xc, w_ih1 + (size_t)d*G4*(2*HH), g1pre + (size_t)d*BB*G4, G4, 2*HH);
  hipLaunchKernelGGL(ln_rows, dim3(2*BB), dim3(256), 0, stream,
      g1pre, ln_ih1_g, ln_ih1_b, BB);

  hipMemsetAsync(hbuf, 0, (size_t)2*BB*HH*sizeof(float), stream);
  hipMemsetAsync(cbuf, 0, (size_t)2*BB*HH*sizeof(float), stream);

  // Layer 1 scan: constant input => reverse scan == forward scan; 48 steps each dir
  for (int t = 0; t < SS; ++t) {
    hipLaunchKernelGGL(gemm_step, dim3(G4/32, 1, 2), dim3(256), 0, stream, hbuf, w_hh1, R);
    hipLaunchKernelGGL(lstm_update, dim3(BB, 2), dim3(256), 0, stream,
        R, g1pre, (long)G4, 0L, 0L,
        ln_hh1_g, ln_hh1_b, ln_ho1_g, ln_ho1_b, hbuf, cbuf);
  }

  hipLaunchKernelGGL(copy_concat, dim3(2*BB*HH/256), dim3(256), 0, stream, hbuf, out);
}